// Round 4
// baseline (174.408 us; speedup 1.0000x reference)
//
#include <hip/hip_runtime.h>
#include <math.h>

#define KTR 96
#define DIM 256
#define PB  40
#define CH  8
#define MDIM 3840
#define KK  512          // [hi | lo*4096] for XT (test/M);  [lo*4096 | hi] for XE (enroll/N)
#define BM 160           // M-tile (test rows: l,j) = 4 phoneme groups
#define BN 64            // N-tile (enroll cols: k,i): 1440 blocks
#define BK 32
#define NTAB 2113        // table nodes, h = 2^-10, x = (i-1056)/1024
#define TPAD 2120

typedef _Float16 v8h __attribute__((ext_vector_type(8)));
typedef float    v4f __attribute__((ext_vector_type(4)));

__device__ __forceinline__ float gate_ref(float x, const float* w, const float* b, const float* v) {
    float g = 0.f;
    #pragma unroll
    for (int c = 0; c < CH; ++c) g = fmaf(v[c], tanhf(fmaf(w[c], x, b[c])), g);
    return g;
}

// ---------------- Kernel 1: L2-normalize + f16 hi/lo split + (extra blocks) gate table ----------------
__global__ __launch_bounds__(256) void k_norm(const float* __restrict__ enroll,
                                              const float* __restrict__ test,
                                              const float* __restrict__ fc1_w,
                                              const float* __restrict__ fc1_b,
                                              const float* __restrict__ fc2_w,
                                              _Float16* __restrict__ XT,
                                              _Float16* __restrict__ XE,
                                              float2* __restrict__ gtabG) {
    int b = blockIdx.x, tid = threadIdx.x;

    if (b >= 2 * KTR) {                       // 9 table-builder blocks
        int i = (b - 2 * KTR) * 256 + tid;
        if (i < NTAB) {
            float w[CH], bb[CH], vv[CH];
            #pragma unroll
            for (int c = 0; c < CH; ++c) { w[c] = fc1_w[c]; bb[c] = fc1_b[c]; vv[c] = fc2_w[c]; }
            float g0 = gate_ref((float)(i - 1056) * 0.0009765625f, w, bb, vv);
            float g1 = gate_ref((float)(i - 1055) * 0.0009765625f, w, bb, vv);
            gtabG[i] = make_float2(g0, g1 - g0);
        }
        return;
    }

    bool isE = (b < KTR);
    int k = isE ? b : b - KTR;
    const float* src = (isE ? enroll : test) + (size_t)k * DIM * PB;

    __shared__ float S[DIM * 41];             // stride 41: conflict-free column walk
    __shared__ float part[6 * PB];
    __shared__ float rn[PB];

    // coalesced float4 stage
    for (int i = tid; i < DIM * PB / 4; i += 256) {
        float4 v = ((const float4*)src)[i];
        int d = i / 10, c = i - d * 10;
        float* p = &S[d * 41 + c * 4];
        p[0] = v.x; p[1] = v.y; p[2] = v.z; p[3] = v.w;
    }
    __syncthreads();
    if (tid < 240) {
        int g = tid / PB, p = tid - (tid / PB) * PB;
        float acc = 0.f;
        for (int d = g; d < DIM; d += 6) {
            float x = S[d * 41 + p];
            acc = fmaf(x, x, acc);
        }
        part[g * PB + p] = acc;
    }
    __syncthreads();
    if (tid < PB) {
        float s = 0.f;
        #pragma unroll
        for (int g = 0; g < 6; ++g) s += part[g * PB + tid];
        rn[tid] = 1.0f / fmaxf(sqrtf(s), 1e-12f);
    }
    __syncthreads();

    // tid == d; stores coalesced 2B along d
    int d = tid;
    for (int p = 0; p < PB; ++p) {
        float v = S[d * 41 + p] * rn[p];
        _Float16 h  = (_Float16)v;
        _Float16 lo = (_Float16)((v - (float)h) * 4096.0f);
        size_t m = (size_t)(k * PB + p);
        if (isE) { XE[m * KK + d] = lo; XE[m * KK + 256 + d] = h;  }
        else     { XT[m * KK + d] = h;  XT[m * KK + 256 + d] = lo; }
    }
}

// ---------------- Kernel 2: LDS-free direct-fragment MFMA GEMM + split-table gate + j-reduction ----------------
// Round-3 post-mortem: the staged structure was DS-pipe bound (10.5 b128 LDS ops/wave-iter =
// ~2000 cy/CU-iter + 8.7M conflict cy vs 50 cy MFMA/SIMD) -- MfmaUtil pinned ~17% at any occupancy.
// Fix: MFMA A/B fragment layout (lane=q4*16+r15 holds 8 contiguous f16 at row r15, k=q4*8) is
// directly global-loadable: 16B/lane, aligned. Tiles are L1/L2-resident (XT+XE = 7.9MB), and the
// VMEM/L1 pipe is separate from DS. No LA/LB, NO per-iter barriers (waves fully independent),
// register double-buffered loads, full unroll -> all k-offsets are immediates (max 960B < 4095).
// LDS holds only split b32 gate tables (merged b64 gather implicated in the 8.7M conflicts).
__global__ __launch_bounds__(256, 2) void k_gemm(const _Float16* __restrict__ XT,
                                                 const _Float16* __restrict__ XE,
                                                 const float2* __restrict__ gtabG,
                                                 float* __restrict__ pho2) {
    __shared__ float gval[TPAD];                      // split tables: b32 random ~2-way (free)
    __shared__ float gslope[TPAD];

    int tid  = threadIdx.x;
    int lane = tid & 63;
    int wv   = tid >> 6;

    for (int i = tid; i < NTAB; i += 256) {
        float2 t = gtabG[i];
        gval[i] = t.x; gslope[i] = t.y;
    }
    __syncthreads();                                  // once, before epilogue use

    int id = blockIdx.y * 60 + blockIdx.x;            // launch index; default XCD = id & 7
    int wg = (id & 7) * 180 + (id >> 3);              // bijective: 180 consecutive tiles per XCD
    int m0 = (wg / 60) * BM;
    int n0 = (wg % 60) * BN;
    int wm = (wv & 1) * 80;
    int wn = (wv >> 1) * 32;
    int r15 = lane & 15;
    int q4  = lane >> 4;

    v4f acc[5][2];
    #pragma unroll
    for (int mt = 0; mt < 5; ++mt)
        #pragma unroll
        for (int nt = 0; nt < 2; ++nt)
            acc[mt][nt] = (v4f)0.f;

    // 7 fragment base pointers; all k-offsets fold into load immediates after unroll
    const _Float16* pa[5];
    const _Float16* pb[2];
    #pragma unroll
    for (int mt = 0; mt < 5; ++mt) pa[mt] = XT + (size_t)(m0 + wm + mt * 16 + r15) * KK + q4 * 8;
    #pragma unroll
    for (int nt = 0; nt < 2; ++nt) pb[nt] = XE + (size_t)(n0 + wn + nt * 16 + r15) * KK + q4 * 8;

    v8h Aa[5], Ab[2], Ba[5], Bb[2];                   // register double buffer

    #define GLD(Sa, Sb, IT) {                                               \
        int ka = ((IT) < 16) ? (IT) * BK : ((IT) - 16) * BK;                \
        int kb = ((IT) < 16) ? (IT) * BK : 256 + ((IT) - 16) * BK;          \
        _Pragma("unroll") for (int mt = 0; mt < 5; ++mt) Sa[mt] = *(const v8h*)(pa[mt] + ka); \
        _Pragma("unroll") for (int nt = 0; nt < 2; ++nt) Sb[nt] = *(const v8h*)(pb[nt] + kb); }

    #define MFMAS(Sa, Sb) {                                                 \
        _Pragma("unroll") for (int mt = 0; mt < 5; ++mt)                    \
        _Pragma("unroll") for (int nt = 0; nt < 2; ++nt)                    \
            acc[mt][nt] = __builtin_amdgcn_mfma_f32_16x16x32_f16(Sa[mt], Sb[nt], acc[mt][nt], 0, 0, 0); }

    GLD(Aa, Ab, 0);
    #pragma unroll
    for (int it = 0; it < 24; it += 2) {
        GLD(Ba, Bb, it + 1);                           // prefetch odd iter
        if (it == 16) {                                // cross terms done: scale by 2^-12 (exact)
            #pragma unroll
            for (int mt = 0; mt < 5; ++mt)
                #pragma unroll
                for (int nt = 0; nt < 2; ++nt)
                    acc[mt][nt] *= 0.000244140625f;
        }
        MFMAS(Aa, Ab);
        if (it + 2 < 24) GLD(Aa, Ab, it + 2);          // prefetch next even iter
        MFMAS(Ba, Bb);
    }
    #undef GLD
    #undef MFMAS

    // ---- epilogue: D row = q4*4+r (test: l,j), col = r15 (enroll: k,i) ----
    const float inv40 = 1.0f / (40.0f + 1e-6f);
    int lg = (m0 + wm) / PB;                           // wave covers groups lg, lg+1
    #pragma unroll
    for (int nt = 0; nt < 2; ++nt) {
        float s0 = 0.f, s1 = 0.f, t2 = 0.f;
        #pragma unroll
        for (int mt = 0; mt < 5; ++mt) {
            #pragma unroll
            for (int r = 0; r < 4; ++r) {
                float x = acc[mt][nt][r];
                float u = fmaf(x, 1024.0f, 1056.0f);
                int i = (int)u;
                i = min(max(i, 0), NTAB - 2);
                float f = u - (float)i;
                float g = fmaf(f, gslope[i], gval[i]);
                float xg = g * x;
                if (mt < 2)       s0 += xg;            // rows 0..31  -> group lg
                else if (mt == 2) t2 += xg;            // rows 32..47 -> straddle
                else              s1 += xg;            // rows 48..79 -> group lg+1
            }
        }
        bool lo = (q4 < 2);                            // mt=2: q4<2 -> rows 32..39 (lg)
        s0 += lo ? t2 : 0.f;
        s1 += lo ? 0.f : t2;
        s0 += __shfl_xor(s0, 16); s0 += __shfl_xor(s0, 32);
        s1 += __shfl_xor(s1, 16); s1 += __shfl_xor(s1, 32);
        if (q4 == 0) {
            int n = n0 + wn + nt * 16 + r15;
            int kk = n / PB, ii = n - kk * PB;
            pho2[((size_t)kk * KTR + lg)     * PB + ii] = s0 * inv40;
            pho2[((size_t)kk * KTR + lg + 1) * PB + ii] = s1 * inv40;
        }
    }
}

// ---------------- Kernel 3: gate (full range -> tanhf) + i-reduction -> [K,K] ----------------
__global__ __launch_bounds__(256) void k_final(const float* __restrict__ pho2,
                                               const float* __restrict__ fc1_w,
                                               const float* __restrict__ fc1_b,
                                               const float* __restrict__ fc2_w,
                                               float* __restrict__ out) {
    int wv = threadIdx.x >> 6;
    int lane = threadIdx.x & 63;
    int pair = blockIdx.x * 4 + wv;

    float w[CH], bb[CH], vv[CH];
    #pragma unroll
    for (int c = 0; c < CH; ++c) { w[c] = fc1_w[c]; bb[c] = fc1_b[c]; vv[c] = fc2_w[c]; }

    float x = (lane < PB) ? pho2[(size_t)pair * PB + lane] : 0.f;
    float s = gate_ref(x, w, bb, vv) * x;

    #pragma unroll
    for (int off = 32; off; off >>= 1) s += __shfl_xor(s, off);
    if (lane == 0) out[pair] = s / (40.0f + 1e-6f);
}

extern "C" void kernel_launch(void* const* d_in, const int* in_sizes, int n_in,
                              void* d_out, int out_size, void* d_ws, size_t ws_size,
                              hipStream_t stream) {
    const float* enroll = (const float*)d_in[0];
    const float* test   = (const float*)d_in[1];
    const float* fc1_w  = (const float*)d_in[2];
    const float* fc1_b  = (const float*)d_in[3];
    const float* fc2_w  = (const float*)d_in[4];
    float* out = (float*)d_out;

    _Float16* XT = (_Float16*)d_ws;                    // [3840][512] f16 (test:  hi|lo')
    _Float16* XE = XT + (size_t)MDIM * KK;             // [3840][512] f16 (enroll: lo'|hi)
    float* pho2  = (float*)(XE + (size_t)MDIM * KK);   // [96*96*40] f32
    float2* gtabG = (float2*)(pho2 + (size_t)KTR * KTR * PB);

    k_norm<<<2 * KTR + 9, 256, 0, stream>>>(enroll, test, fc1_w, fc1_b, fc2_w, XT, XE, gtabG);
    dim3 g2(MDIM / BN, MDIM / BM);                     // (60, 24)
    k_gemm<<<g2, 256, 0, stream>>>(XT, XE, gtabG, pho2);
    k_final<<<KTR * KTR / 4, 256, 0, stream>>>(pho2, fc1_w, fc1_b, fc2_w, out);
}

// Round 5
// 161.724 us; speedup vs baseline: 1.0784x; 1.0784x over previous
//
#include <hip/hip_runtime.h>
#include <math.h>

#define KTR 96
#define DIM 256
#define PB  40
#define CH  8
#define MDIM 3840
#define KK  512          // [hi | lo*4096] for XT (test/M);  [lo*4096 | hi] for XE (enroll/N)
#define BM 160           // M-tile (test rows: l,j) = 4 phoneme groups
#define BN 128           // N-tile (enroll cols: k,i): 720 blocks
#define BK 32
#define LDA 40           // f16 elems per LDS row (32 + 8 pad)
#define NTAB 2113        // table nodes, h = 2^-10, x = (i-1056)/1024
#define TPAD 2120

typedef _Float16 v8h __attribute__((ext_vector_type(8)));
typedef float    v4f __attribute__((ext_vector_type(4)));

__device__ __forceinline__ float gate_ref(float x, const float* w, const float* b, const float* v) {
    float g = 0.f;
    #pragma unroll
    for (int c = 0; c < CH; ++c) g = fmaf(v[c], tanhf(fmaf(w[c], x, b[c])), g);
    return g;
}

// ---------------- Kernel 1: L2-normalize + f16 hi/lo split + (extra blocks) gate table ----------------
__global__ __launch_bounds__(256) void k_norm(const float* __restrict__ enroll,
                                              const float* __restrict__ test,
                                              const float* __restrict__ fc1_w,
                                              const float* __restrict__ fc1_b,
                                              const float* __restrict__ fc2_w,
                                              _Float16* __restrict__ XT,
                                              _Float16* __restrict__ XE,
                                              float2* __restrict__ gtabG) {
    int b = blockIdx.x, tid = threadIdx.x;

    if (b >= 2 * KTR) {                       // 9 table-builder blocks
        int i = (b - 2 * KTR) * 256 + tid;
        if (i < NTAB) {
            float w[CH], bb[CH], vv[CH];
            #pragma unroll
            for (int c = 0; c < CH; ++c) { w[c] = fc1_w[c]; bb[c] = fc1_b[c]; vv[c] = fc2_w[c]; }
            float g0 = gate_ref((float)(i - 1056) * 0.0009765625f, w, bb, vv);
            float g1 = gate_ref((float)(i - 1055) * 0.0009765625f, w, bb, vv);
            gtabG[i] = make_float2(g0, g1 - g0);
        }
        return;
    }

    bool isE = (b < KTR);
    int k = isE ? b : b - KTR;
    const float* src = (isE ? enroll : test) + (size_t)k * DIM * PB;

    __shared__ float S[DIM * 41];             // stride 41: conflict-free column walk
    __shared__ float part[6 * PB];
    __shared__ float rn[PB];

    // coalesced float4 stage
    for (int i = tid; i < DIM * PB / 4; i += 256) {
        float4 v = ((const float4*)src)[i];
        int d = i / 10, c = i - d * 10;
        float* p = &S[d * 41 + c * 4];
        p[0] = v.x; p[1] = v.y; p[2] = v.z; p[3] = v.w;
    }
    __syncthreads();
    if (tid < 240) {
        int g = tid / PB, p = tid - (tid / PB) * PB;
        float acc = 0.f;
        for (int d = g; d < DIM; d += 6) {
            float x = S[d * 41 + p];
            acc = fmaf(x, x, acc);
        }
        part[g * PB + p] = acc;
    }
    __syncthreads();
    if (tid < PB) {
        float s = 0.f;
        #pragma unroll
        for (int g = 0; g < 6; ++g) s += part[g * PB + tid];
        rn[tid] = 1.0f / fmaxf(sqrtf(s), 1e-12f);
    }
    __syncthreads();

    // tid == d; stores coalesced 2B along d
    int d = tid;
    for (int p = 0; p < PB; ++p) {
        float v = S[d * 41 + p] * rn[p];
        _Float16 h  = (_Float16)v;
        _Float16 lo = (_Float16)((v - (float)h) * 4096.0f);
        size_t m = (size_t)(k * PB + p);
        if (isE) { XE[m * KK + d] = lo; XE[m * KK + 256 + d] = h;  }
        else     { XT[m * KK + d] = h;  XT[m * KK + 256 + d] = lo; }
    }
}

// ---------------- Kernel 2: A-in-LDS / B-direct split-f16 MFMA GEMM + split-table gate + j-reduction ----------------
// r0 structure (measured best ~43us) with B removed from LDS:
//  - A reg-staged into padded LDS (LDA=40), 2-barrier dbuf -- barriers bound the scheduler, no r4 spill mode.
//  - B fragments (16B/lane, MFMA-native layout) loaded DIRECT from global, register ping-pong one iter ahead.
//    Deletes 8 ds_write + 16 ds_read instr/block-iter: DS pipe ~650cy -> ~360cy vs 384cy MFMA (balanced);
//    B bytes move to the otherwise-idle VMEM/L2 pipe.
//  - Split b32 gate tables (r3's merged-float2 b64 gather caused 8.7M vs 1.95M conflict cycles).
//  - Bijective XCD swizzle: 720 % 8 == 0, 90 consecutive tiles/XCD = 3 whole M-panels (~4.4MB, L2-resident).
__global__ __launch_bounds__(256, 2) void k_gemm(const _Float16* __restrict__ XT,
                                                 const _Float16* __restrict__ XE,
                                                 const float2* __restrict__ gtabG,
                                                 float* __restrict__ pho2) {
    __shared__ __align__(16) _Float16 LA[BM * LDA];   // 12800 B  (test rows only)
    __shared__ float gval[TPAD];                      // split tables: b32 random ~2-way (free)
    __shared__ float gslope[TPAD];
    // total 29760 B

    int tid  = threadIdx.x;
    int lane = tid & 63;
    int wv   = tid >> 6;

    for (int i = tid; i < NTAB; i += 256) {
        float2 t = gtabG[i];
        gval[i] = t.x; gslope[i] = t.y;
    }

    int id = blockIdx.y * 30 + blockIdx.x;            // 720 blocks
    int wg = (id & 7) * 90 + (id >> 3);               // bijective: 90 consecutive tiles per XCD
    int m0 = (wg / 30) * BM;
    int n0 = (wg % 30) * BN;
    int wm = (wv & 1) * 80;
    int wn = (wv >> 1) * 64;
    int r15 = lane & 15;
    int q4  = lane >> 4;

    v4f acc[5][4];
    #pragma unroll
    for (int mt = 0; mt < 5; ++mt)
        #pragma unroll
        for (int nt = 0; nt < 4; ++nt)
            acc[mt][nt] = (v4f)0.f;

    int aoff[5];
    #pragma unroll
    for (int mt = 0; mt < 5; ++mt) aoff[mt] = (wm + mt * 16 + r15) * LDA + q4 * 8;

    // B fragment base pointers: MFMA-native, 16B/lane, direct from global (L2-resident panel)
    const _Float16* pb[4];
    #pragma unroll
    for (int nt = 0; nt < 4; ++nt) pb[nt] = XE + (size_t)(n0 + wn + nt * 16 + r15) * KK + q4 * 8;

    // A staging: 64 rows x 4 16B-chunks per 256 threads
    int arow = tid >> 2, aqc = tid & 3;
    const uint4* gT = (const uint4*)(XT + (size_t)(m0 + arow) * KK);  // 64 uint4 per row
    uint4* lA = (uint4*)LA + (arow * 5 + aqc);

    uint4 va0, va1, va2;
    #define LOADSA(IT) {                                                    \
        int ka = ((IT) < 16) ? (IT) * BK : ((IT) - 16) * BK;                \
        int ia = (ka >> 3) + aqc;                                           \
        va0 = gT[ia]; va1 = gT[ia + 64 * 64];                               \
        if (tid < 128) va2 = gT[ia + 128 * 64]; }

    v8h B0[4], B1[4];                                 // register ping-pong for B fragments
    #define GLDB(Sb, IT) {                                                  \
        int kb = ((IT) < 16) ? (IT) * BK : 256 + ((IT) - 16) * BK;          \
        _Pragma("unroll") for (int nt = 0; nt < 4; ++nt) Sb[nt] = *(const v8h*)(pb[nt] + kb); }

    #define MFMAS(AF, BF) {                                                 \
        _Pragma("unroll") for (int mt = 0; mt < 5; ++mt)                    \
        _Pragma("unroll") for (int nt = 0; nt < 4; ++nt)                    \
            acc[mt][nt] = __builtin_amdgcn_mfma_f32_16x16x32_f16(AF[mt], BF[nt], acc[mt][nt], 0, 0, 0); }

    LOADSA(0);
    GLDB(B0, 0);
    #pragma unroll
    for (int it = 0; it < 24; ++it) {
        __syncthreads();                               // prev iter's LDS frag reads done
        lA[0]   = va0;
        lA[320] = va1;                                 // +64 rows * 5 chunks
        if (tid < 128) lA[640] = va2;                  // rows 128..159
        __syncthreads();

        if (it < 23) {                                 // prefetch overlaps MFMA below
            LOADSA(it + 1);
            if (it & 1) { GLDB(B0, it + 1) } else { GLDB(B1, it + 1) }
        }

        if (it == 16) {                                // cross terms done: scale by 2^-12 (exact)
            #pragma unroll
            for (int mt = 0; mt < 5; ++mt)
                #pragma unroll
                for (int nt = 0; nt < 4; ++nt)
                    acc[mt][nt] *= 0.000244140625f;
        }

        v8h af[5];
        #pragma unroll
        for (int mt = 0; mt < 5; ++mt) af[mt] = *(const v8h*)(LA + aoff[mt]);
        if (it & 1) { MFMAS(af, B1) } else { MFMAS(af, B0) }
    }
    #undef LOADSA
    #undef GLDB
    #undef MFMAS

    // ---- epilogue: D row = q4*4+r (test: l,j), col = r15 (enroll: k,i) ----
    const float inv40 = 1.0f / (40.0f + 1e-6f);
    int lg = (m0 + wm) / PB;                           // wave covers groups lg, lg+1
    #pragma unroll
    for (int nt = 0; nt < 4; ++nt) {
        float s0 = 0.f, s1 = 0.f, t2 = 0.f;
        #pragma unroll
        for (int mt = 0; mt < 5; ++mt) {
            #pragma unroll
            for (int r = 0; r < 4; ++r) {
                float x = acc[mt][nt][r];
                float u = fmaf(x, 1024.0f, 1056.0f);
                int i = (int)u;
                i = min(max(i, 0), NTAB - 2);
                float f = u - (float)i;
                float g = fmaf(f, gslope[i], gval[i]);
                float xg = g * x;
                if (mt < 2)       s0 += xg;            // rows 0..31  -> group lg
                else if (mt == 2) t2 += xg;            // rows 32..47 -> straddle
                else              s1 += xg;            // rows 48..79 -> group lg+1
            }
        }
        bool lo = (q4 < 2);                            // mt=2: q4<2 -> rows 32..39 (lg)
        s0 += lo ? t2 : 0.f;
        s1 += lo ? 0.f : t2;
        s0 += __shfl_xor(s0, 16); s0 += __shfl_xor(s0, 32);
        s1 += __shfl_xor(s1, 16); s1 += __shfl_xor(s1, 32);
        if (q4 == 0) {
            int n = n0 + wn + nt * 16 + r15;
            int kk = n / PB, ii = n - kk * PB;
            pho2[((size_t)kk * KTR + lg)     * PB + ii] = s0 * inv40;
            pho2[((size_t)kk * KTR + lg + 1) * PB + ii] = s1 * inv40;
        }
    }
}

// ---------------- Kernel 3: gate (full range -> tanhf) + i-reduction -> [K,K] ----------------
__global__ __launch_bounds__(256) void k_final(const float* __restrict__ pho2,
                                               const float* __restrict__ fc1_w,
                                               const float* __restrict__ fc1_b,
                                               const float* __restrict__ fc2_w,
                                               float* __restrict__ out) {
    int wv = threadIdx.x >> 6;
    int lane = threadIdx.x & 63;
    int pair = blockIdx.x * 4 + wv;

    float w[CH], bb[CH], vv[CH];
    #pragma unroll
    for (int c = 0; c < CH; ++c) { w[c] = fc1_w[c]; bb[c] = fc1_b[c]; vv[c] = fc2_w[c]; }

    float x = (lane < PB) ? pho2[(size_t)pair * PB + lane] : 0.f;
    float s = gate_ref(x, w, bb, vv) * x;

    #pragma unroll
    for (int off = 32; off; off >>= 1) s += __shfl_xor(s, off);
    if (lane == 0) out[pair] = s / (40.0f + 1e-6f);
}

extern "C" void kernel_launch(void* const* d_in, const int* in_sizes, int n_in,
                              void* d_out, int out_size, void* d_ws, size_t ws_size,
                              hipStream_t stream) {
    const float* enroll = (const float*)d_in[0];
    const float* test   = (const float*)d_in[1];
    const float* fc1_w  = (const float*)d_in[2];
    const float* fc1_b  = (const float*)d_in[3];
    const float* fc2_w  = (const float*)d_in[4];
    float* out = (float*)d_out;

    _Float16* XT = (_Float16*)d_ws;                    // [3840][512] f16 (test:  hi|lo')
    _Float16* XE = XT + (size_t)MDIM * KK;             // [3840][512] f16 (enroll: lo'|hi)
    float* pho2  = (float*)(XE + (size_t)MDIM * KK);   // [96*96*40] f32
    float2* gtabG = (float2*)(pho2 + (size_t)KTR * KTR * PB);

    k_norm<<<2 * KTR + 9, 256, 0, stream>>>(enroll, test, fc1_w, fc1_b, fc2_w, XT, XE, gtabG);
    dim3 g2(MDIM / BN, MDIM / BM);                     // (30, 24)
    k_gemm<<<g2, 256, 0, stream>>>(XT, XE, gtabG, pho2);
    k_final<<<KTR * KTR / 4, 256, 0, stream>>>(pho2, fc1_w, fc1_b, fc2_w, out);
}

// Round 6
// 139.330 us; speedup vs baseline: 1.2518x; 1.1607x over previous
//
#include <hip/hip_runtime.h>
#include <math.h>

#define KTR 96
#define DIM 256
#define PB  40
#define CH  8
#define MDIM 3840
#define KK  512          // [hi | lo*4096] for XT (test/M);  [lo*4096 | hi] for XE (enroll/N)
#define BM 160           // M-tile (test rows: l,j) = 4 phoneme groups
#define BN 128           // N-tile (enroll cols: k,i): 720 blocks
#define BK 32
#define LDA 40           // f16 elems per LDS row (32 + 8 pad)
#define NTAB 2113        // table nodes, h = 2^-10, x = (i-1056)/1024
#define TPAD 2120

typedef _Float16 v8h __attribute__((ext_vector_type(8)));
typedef float    v4f __attribute__((ext_vector_type(4)));

__device__ __forceinline__ float gate_ref(float x, const float* w, const float* b, const float* v) {
    float g = 0.f;
    #pragma unroll
    for (int c = 0; c < CH; ++c) g = fmaf(v[c], tanhf(fmaf(w[c], x, b[c])), g);
    return g;
}

// ---------------- Kernel 1: L2-normalize + f16 hi/lo split + (extra blocks) gate table ----------------
__global__ __launch_bounds__(256) void k_norm(const float* __restrict__ enroll,
                                              const float* __restrict__ test,
                                              const float* __restrict__ fc1_w,
                                              const float* __restrict__ fc1_b,
                                              const float* __restrict__ fc2_w,
                                              _Float16* __restrict__ XT,
                                              _Float16* __restrict__ XE,
                                              float2* __restrict__ gtabG) {
    int b = blockIdx.x, tid = threadIdx.x;

    if (b >= 2 * KTR) {                       // 9 table-builder blocks
        int i = (b - 2 * KTR) * 256 + tid;
        if (i < NTAB) {
            float w[CH], bb[CH], vv[CH];
            #pragma unroll
            for (int c = 0; c < CH; ++c) { w[c] = fc1_w[c]; bb[c] = fc1_b[c]; vv[c] = fc2_w[c]; }
            float g0 = gate_ref((float)(i - 1056) * 0.0009765625f, w, bb, vv);
            float g1 = gate_ref((float)(i - 1055) * 0.0009765625f, w, bb, vv);
            gtabG[i] = make_float2(g0, g1 - g0);
        }
        return;
    }

    bool isE = (b < KTR);
    int k = isE ? b : b - KTR;
    const float* src = (isE ? enroll : test) + (size_t)k * DIM * PB;

    __shared__ float S[DIM * 41];             // stride 41: conflict-free column walk
    __shared__ float part[6 * PB];
    __shared__ float rn[PB];

    // coalesced float4 stage
    for (int i = tid; i < DIM * PB / 4; i += 256) {
        float4 v = ((const float4*)src)[i];
        int d = i / 10, c = i - d * 10;
        float* p = &S[d * 41 + c * 4];
        p[0] = v.x; p[1] = v.y; p[2] = v.z; p[3] = v.w;
    }
    __syncthreads();
    if (tid < 240) {
        int g = tid / PB, p = tid - (tid / PB) * PB;
        float acc = 0.f;
        for (int d = g; d < DIM; d += 6) {
            float x = S[d * 41 + p];
            acc = fmaf(x, x, acc);
        }
        part[g * PB + p] = acc;
    }
    __syncthreads();
    if (tid < PB) {
        float s = 0.f;
        #pragma unroll
        for (int g = 0; g < 6; ++g) s += part[g * PB + tid];
        rn[tid] = 1.0f / fmaxf(sqrtf(s), 1e-12f);
    }
    __syncthreads();

    // tid == d; stores coalesced 2B along d
    int d = tid;
    for (int p = 0; p < PB; ++p) {
        float v = S[d * 41 + p] * rn[p];
        _Float16 h  = (_Float16)v;
        _Float16 lo = (_Float16)((v - (float)h) * 4096.0f);
        size_t m = (size_t)(k * PB + p);
        if (isE) { XE[m * KK + d] = lo; XE[m * KK + 256 + d] = h;  }
        else     { XT[m * KK + d] = h;  XT[m * KK + 256 + d] = lo; }
    }
}

// ---------------- Kernel 2: A-in-LDS / B-direct split-f16 MFMA GEMM + split-table gate + j-reduction ----------------
// r5's operand placement with r5's spill trigger removed:
//  - ROLLED K-loop (NO #pragma unroll): full unroll was the proven spill trigger in r4 AND r5
//    (24 exposed load sites -> scheduler hoisting -> live-range blowup -> 40-55MB scratch writes).
//    Rolled loop + per-iter barriers bound hoisting to one iteration; r0/r1/r3 never spilled this way.
//  - A reg-staged into padded LDS (LDA=40), 2-barrier structure exactly as r0 (measured best, 43us).
//  - B fragments (MFMA-native, 16B/lane) direct from global with named 2-deep ping-pong (B0/B1).
//    Cuts per-wave-iter DS ops 13.5 -> 7.5 b128 (~648 -> ~360cy/block-iter vs 384cy MFMA).
//    Per-instr B pattern: 16 rows x 64B contiguous segments; XE n-panel (128KB) L2-resident.
//  - Split b32 gate tables (merged b64 gather measured 4.5x the conflict cycles).
//  - launch_bounds(256,2): 256-reg cap. r2 proved cap=128 spills this register set.
//  - Bijective XCD swizzle (720 % 8 == 0): 90 consecutive tiles/XCD = 3 whole M-panels.
__global__ __launch_bounds__(256, 2) void k_gemm(const _Float16* __restrict__ XT,
                                                 const _Float16* __restrict__ XE,
                                                 const float2* __restrict__ gtabG,
                                                 float* __restrict__ pho2) {
    __shared__ __align__(16) _Float16 LA[BM * LDA];   // 12800 B  (test rows only)
    __shared__ float gval[TPAD];                      // split tables: b32 random ~2-way (free)
    __shared__ float gslope[TPAD];
    // total 29760 B

    int tid  = threadIdx.x;
    int lane = tid & 63;
    int wv   = tid >> 6;

    for (int i = tid; i < NTAB; i += 256) {
        float2 t = gtabG[i];
        gval[i] = t.x; gslope[i] = t.y;
    }

    int id = blockIdx.y * 30 + blockIdx.x;            // 720 blocks
    int wg = (id & 7) * 90 + (id >> 3);               // bijective: 90 consecutive tiles per XCD
    int m0 = (wg / 30) * BM;
    int n0 = (wg % 30) * BN;
    int wm = (wv & 1) * 80;
    int wn = (wv >> 1) * 64;
    int r15 = lane & 15;
    int q4  = lane >> 4;

    v4f acc[5][4];
    #pragma unroll
    for (int mt = 0; mt < 5; ++mt)
        #pragma unroll
        for (int nt = 0; nt < 4; ++nt)
            acc[mt][nt] = (v4f)0.f;

    int aoff[5];
    #pragma unroll
    for (int mt = 0; mt < 5; ++mt) aoff[mt] = (wm + mt * 16 + r15) * LDA + q4 * 8;

    // B fragment base pointers: MFMA-native, 16B/lane, direct from global (L2-resident panel)
    const _Float16* pb[4];
    #pragma unroll
    for (int nt = 0; nt < 4; ++nt) pb[nt] = XE + (size_t)(n0 + wn + nt * 16 + r15) * KK + q4 * 8;

    // A staging: 64 rows x 4 16B-chunks per 256 threads
    int arow = tid >> 2, aqc = tid & 3;
    const uint4* gT = (const uint4*)(XT + (size_t)(m0 + arow) * KK);  // 64 uint4 per row
    uint4* lA = (uint4*)LA + (arow * 5 + aqc);

    uint4 va0, va1, va2;
    #define LOADSA(IT) {                                                    \
        int ka = ((IT) < 16) ? (IT) * BK : ((IT) - 16) * BK;                \
        int ia = (ka >> 3) + aqc;                                           \
        va0 = gT[ia]; va1 = gT[ia + 64 * 64];                               \
        if (tid < 128) va2 = gT[ia + 128 * 64]; }

    v8h B0[4], B1[4];                                 // named register ping-pong for B fragments
    #define GLDB(Sb, IT) {                                                  \
        int kb = ((IT) < 16) ? (IT) * BK : 256 + ((IT) - 16) * BK;          \
        _Pragma("unroll") for (int nt = 0; nt < 4; ++nt) Sb[nt] = *(const v8h*)(pb[nt] + kb); }

    #define MFMAS(AF, BF) {                                                 \
        _Pragma("unroll") for (int mt = 0; mt < 5; ++mt)                    \
        _Pragma("unroll") for (int nt = 0; nt < 4; ++nt)                    \
            acc[mt][nt] = __builtin_amdgcn_mfma_f32_16x16x32_f16(AF[mt], BF[nt], acc[mt][nt], 0, 0, 0); }

    LOADSA(0);
    GLDB(B0, 0);
    for (int it = 0; it < 24; ++it) {                  // ROLLED: no unroll pragma (spill guard)
        __syncthreads();                               // prev iter's LDS frag reads done
        lA[0]   = va0;
        lA[320] = va1;                                 // +64 rows * 5 chunks
        if (tid < 128) lA[640] = va2;                  // rows 128..159
        __syncthreads();

        if (it < 23) {                                 // prefetch overlaps MFMA below
            LOADSA(it + 1);
            if (it & 1) { GLDB(B0, it + 1) } else { GLDB(B1, it + 1) }
        }

        if (it == 16) {                                // cross terms done: scale by 2^-12 (exact)
            #pragma unroll
            for (int mt = 0; mt < 5; ++mt)
                #pragma unroll
                for (int nt = 0; nt < 4; ++nt)
                    acc[mt][nt] *= 0.000244140625f;
        }

        v8h af[5];
        #pragma unroll
        for (int mt = 0; mt < 5; ++mt) af[mt] = *(const v8h*)(LA + aoff[mt]);
        if (it & 1) { MFMAS(af, B1) } else { MFMAS(af, B0) }
    }
    #undef LOADSA
    #undef GLDB
    #undef MFMAS

    // ---- epilogue: D row = q4*4+r (test: l,j), col = r15 (enroll: k,i) ----
    const float inv40 = 1.0f / (40.0f + 1e-6f);
    int lg = (m0 + wm) / PB;                           // wave covers groups lg, lg+1
    #pragma unroll
    for (int nt = 0; nt < 4; ++nt) {
        float s0 = 0.f, s1 = 0.f, t2 = 0.f;
        #pragma unroll
        for (int mt = 0; mt < 5; ++mt) {
            #pragma unroll
            for (int r = 0; r < 4; ++r) {
                float x = acc[mt][nt][r];
                float u = fmaf(x, 1024.0f, 1056.0f);
                int i = (int)u;
                i = min(max(i, 0), NTAB - 2);
                float f = u - (float)i;
                float g = fmaf(f, gslope[i], gval[i]);
                float xg = g * x;
                if (mt < 2)       s0 += xg;            // rows 0..31  -> group lg
                else if (mt == 2) t2 += xg;            // rows 32..47 -> straddle
                else              s1 += xg;            // rows 48..79 -> group lg+1
            }
        }
        bool lo = (q4 < 2);                            // mt=2: q4<2 -> rows 32..39 (lg)
        s0 += lo ? t2 : 0.f;
        s1 += lo ? 0.f : t2;
        s0 += __shfl_xor(s0, 16); s0 += __shfl_xor(s0, 32);
        s1 += __shfl_xor(s1, 16); s1 += __shfl_xor(s1, 32);
        if (q4 == 0) {
            int n = n0 + wn + nt * 16 + r15;
            int kk = n / PB, ii = n - kk * PB;
            pho2[((size_t)kk * KTR + lg)     * PB + ii] = s0 * inv40;
            pho2[((size_t)kk * KTR + lg + 1) * PB + ii] = s1 * inv40;
        }
    }
}

// ---------------- Kernel 3: gate (full range -> tanhf) + i-reduction -> [K,K] ----------------
__global__ __launch_bounds__(256) void k_final(const float* __restrict__ pho2,
                                               const float* __restrict__ fc1_w,
                                               const float* __restrict__ fc1_b,
                                               const float* __restrict__ fc2_w,
                                               float* __restrict__ out) {
    int wv = threadIdx.x >> 6;
    int lane = threadIdx.x & 63;
    int pair = blockIdx.x * 4 + wv;

    float w[CH], bb[CH], vv[CH];
    #pragma unroll
    for (int c = 0; c < CH; ++c) { w[c] = fc1_w[c]; bb[c] = fc1_b[c]; vv[c] = fc2_w[c]; }

    float x = (lane < PB) ? pho2[(size_t)pair * PB + lane] : 0.f;
    float s = gate_ref(x, w, bb, vv) * x;

    #pragma unroll
    for (int off = 32; off; off >>= 1) s += __shfl_xor(s, off);
    if (lane == 0) out[pair] = s / (40.0f + 1e-6f);
}

extern "C" void kernel_launch(void* const* d_in, const int* in_sizes, int n_in,
                              void* d_out, int out_size, void* d_ws, size_t ws_size,
                              hipStream_t stream) {
    const float* enroll = (const float*)d_in[0];
    const float* test   = (const float*)d_in[1];
    const float* fc1_w  = (const float*)d_in[2];
    const float* fc1_b  = (const float*)d_in[3];
    const float* fc2_w  = (const float*)d_in[4];
    float* out = (float*)d_out;

    _Float16* XT = (_Float16*)d_ws;                    // [3840][512] f16 (test:  hi|lo')
    _Float16* XE = XT + (size_t)MDIM * KK;             // [3840][512] f16 (enroll: lo'|hi)
    float* pho2  = (float*)(XE + (size_t)MDIM * KK);   // [96*96*40] f32
    float2* gtabG = (float2*)(pho2 + (size_t)KTR * KTR * PB);

    k_norm<<<2 * KTR + 9, 256, 0, stream>>>(enroll, test, fc1_w, fc1_b, fc2_w, XT, XE, gtabG);
    dim3 g2(MDIM / BN, MDIM / BM);                     // (30, 24)
    k_gemm<<<g2, 256, 0, stream>>>(XT, XE, gtabG, pho2);
    k_final<<<KTR * KTR / 4, 256, 0, stream>>>(pho2, fc1_w, fc1_b, fc2_w, out);
}

// Round 7
// 111.999 us; speedup vs baseline: 1.5572x; 1.2440x over previous
//
#include <hip/hip_runtime.h>
#include <math.h>

#define KTR 96
#define DIM 256
#define PB  40
#define CH  8
#define MDIM 3840
#define KK  512          // [hi | lo*4096] for XT (test/M);  [lo*4096 | hi] for XE (enroll/N)
#define BM 160           // M-tile (test rows: l,j) = 4 phoneme groups
#define BN 128           // N-tile (enroll cols: k,i)
#define BK 32
#define LDA 40           // f16 elems per LDS row (32 + 8 pad)
#define NTAB 2113        // table nodes, h = 2^-10, x = (i-1056)/1024
#define TPAD 2120

typedef _Float16 v8h __attribute__((ext_vector_type(8)));
typedef float    v4f __attribute__((ext_vector_type(4)));

__device__ __forceinline__ float gate_ref(float x, const float* w, const float* b, const float* v) {
    float g = 0.f;
    #pragma unroll
    for (int c = 0; c < CH; ++c) g = fmaf(v[c], tanhf(fmaf(w[c], x, b[c])), g);
    return g;
}

// ---------------- Kernel 1: L2-normalize + f16 hi/lo split + (extra blocks) gate table ----------------
__global__ __launch_bounds__(256) void k_norm(const float* __restrict__ enroll,
                                              const float* __restrict__ test,
                                              const float* __restrict__ fc1_w,
                                              const float* __restrict__ fc1_b,
                                              const float* __restrict__ fc2_w,
                                              _Float16* __restrict__ XT,
                                              _Float16* __restrict__ XE,
                                              float2* __restrict__ gtabG) {
    int b = blockIdx.x, tid = threadIdx.x;

    if (b >= 2 * KTR) {                       // 9 table-builder blocks
        int i = (b - 2 * KTR) * 256 + tid;
        if (i < NTAB) {
            float w[CH], bb[CH], vv[CH];
            #pragma unroll
            for (int c = 0; c < CH; ++c) { w[c] = fc1_w[c]; bb[c] = fc1_b[c]; vv[c] = fc2_w[c]; }
            float g0 = gate_ref((float)(i - 1056) * 0.0009765625f, w, bb, vv);
            float g1 = gate_ref((float)(i - 1055) * 0.0009765625f, w, bb, vv);
            gtabG[i] = make_float2(g0, g1 - g0);
        }
        return;
    }

    bool isE = (b < KTR);
    int k = isE ? b : b - KTR;
    const float* src = (isE ? enroll : test) + (size_t)k * DIM * PB;

    __shared__ float S[DIM * 41];             // stride 41: conflict-free column walk
    __shared__ float part[6 * PB];
    __shared__ float rn[PB];

    // coalesced float4 stage
    for (int i = tid; i < DIM * PB / 4; i += 256) {
        float4 v = ((const float4*)src)[i];
        int d = i / 10, c = i - d * 10;
        float* p = &S[d * 41 + c * 4];
        p[0] = v.x; p[1] = v.y; p[2] = v.z; p[3] = v.w;
    }
    __syncthreads();
    if (tid < 240) {
        int g = tid / PB, p = tid - (tid / PB) * PB;
        float acc = 0.f;
        for (int d = g; d < DIM; d += 6) {
            float x = S[d * 41 + p];
            acc = fmaf(x, x, acc);
        }
        part[g * PB + p] = acc;
    }
    __syncthreads();
    if (tid < PB) {
        float s = 0.f;
        #pragma unroll
        for (int g = 0; g < 6; ++g) s += part[g * PB + tid];
        rn[tid] = 1.0f / fmaxf(sqrtf(s), 1e-12f);
    }
    __syncthreads();

    // tid == d; stores coalesced 2B along d
    int d = tid;
    for (int p = 0; p < PB; ++p) {
        float v = S[d * 41 + p] * rn[p];
        _Float16 h  = (_Float16)v;
        _Float16 lo = (_Float16)((v - (float)h) * 4096.0f);
        size_t m = (size_t)(k * PB + p);
        if (isE) { XE[m * KK + d] = lo; XE[m * KK + 256 + d] = h;  }
        else     { XT[m * KK + d] = h;  XT[m * KK + 256 + d] = lo; }
    }
}

// ---------------- Kernel 2: pipelined split-f16 MFMA GEMM + table gate + j-reduction ----------------
// r0 structure VERBATIM (session best: k_gemm ~43us, 527 TF) -- every structural deviation tried
// in r1-r6 (gload_lds, BN=64, full unroll, B-direct) regressed 15-150%; spill triggers were
// full-unroll hoisting (r4/r5) and launch-bounds reg caps (r2). Only delta vs r0: bijective
// 2-D XCD chunking (T1). Each XCD owns 6 M-panels x 15 N-panels: working set 6*160KB(A) +
// 15*128KB(B) = 2.9MB < 4MB L2/XCD (1-D chunking would be 4.3MB, overflows).
__global__ __launch_bounds__(256, 3) void k_gemm(const _Float16* __restrict__ XT,
                                                 const _Float16* __restrict__ XE,
                                                 const float2* __restrict__ gtabG,
                                                 float* __restrict__ pho2) {
    __shared__ __align__(16) _Float16 LA[BM * LDA];   // 12800 B  (test rows)
    __shared__ __align__(16) _Float16 LB[BN * LDA];   // 10240 B  (enroll rows)
    __shared__ float gval[TPAD];                      // split tables: b32 random ~2-way (free)
    __shared__ float gslope[TPAD];

    int tid  = threadIdx.x;
    int lane = tid & 63;
    int wv   = tid >> 6;

    for (int i = tid; i < NTAB; i += 256) {
        float2 t = gtabG[i];
        gval[i] = t.x; gslope[i] = t.y;
    }

    // Bijective 2-D XCD chunk: XCD = id&7 (round-robin dispatch), 90 tiles/XCD as 6m x 15n.
    int id  = blockIdx.y * 30 + blockIdx.x;           // 720 blocks
    int xcd = id & 7;
    int loc = id >> 3;                                // 0..89 within XCD
    int nI  = (xcd & 1) * 15 + loc % 15;              // 30 n-tiles = 2 XCD-cols x 15
    int mI  = (xcd >> 1) * 6 + loc / 15;              // 24 m-tiles = 4 XCD-rows x 6
    int m0 = mI * BM;
    int n0 = nI * BN;
    int wm = (wv & 1) * 80;
    int wn = (wv >> 1) * 64;
    int r15 = lane & 15;
    int q4  = lane >> 4;

    v4f acc[5][4];
    #pragma unroll
    for (int mt = 0; mt < 5; ++mt)
        #pragma unroll
        for (int nt = 0; nt < 4; ++nt)
            acc[mt][nt] = (v4f)0.f;

    int aoff[5], boff[4];
    #pragma unroll
    for (int mt = 0; mt < 5; ++mt) aoff[mt] = (wm + mt * 16 + r15) * LDA + q4 * 8;
    #pragma unroll
    for (int nt = 0; nt < 4; ++nt) boff[nt] = (wn + nt * 16 + r15) * LDA + q4 * 8;

    int arow = tid >> 2, aqc = tid & 3;               // 64 rows x 4 chunks
    const uint4* gT = (const uint4*)(XT + (size_t)(m0 + arow) * KK);  // 64 uint4 per row
    const uint4* gE = (const uint4*)(XE + (size_t)(n0 + arow) * KK);
    uint4* lA = (uint4*)LA + (arow * 5 + aqc);
    uint4* lB = (uint4*)LB + (arow * 5 + aqc);

    uint4 va0, va1, va2, vb0, vb1;
    #define LOADS(IT) {                                                     \
        int ka = ((IT) < 16) ? (IT) * BK : ((IT) - 16) * BK;                \
        int kb = ((IT) < 16) ? (IT) * BK : 256 + ((IT) - 16) * BK;          \
        int ia = (ka >> 3) + aqc, ib = (kb >> 3) + aqc;                     \
        va0 = gT[ia]; va1 = gT[ia + 64 * 64];                               \
        if (tid < 128) va2 = gT[ia + 128 * 64];                             \
        vb0 = gE[ib]; vb1 = gE[ib + 64 * 64]; }

    LOADS(0);
    for (int it = 0; it < 24; ++it) {
        __syncthreads();                               // prev iter's frag reads done
        lA[0]   = va0;
        lA[320] = va1;                                 // +64 rows * 5 chunks
        if (tid < 128) lA[640] = va2;                  // rows 128..159
        lB[0]   = vb0;
        lB[320] = vb1;
        __syncthreads();

        if (it < 23) LOADS(it + 1);                    // prefetch overlaps MFMA below

        if (it == 16) {                                // cross terms done: scale by 2^-12 (exact)
            #pragma unroll
            for (int mt = 0; mt < 5; ++mt)
                #pragma unroll
                for (int nt = 0; nt < 4; ++nt)
                    acc[mt][nt] *= 0.000244140625f;
        }

        v8h af[5], bf[4];
        #pragma unroll
        for (int mt = 0; mt < 5; ++mt) af[mt] = *(const v8h*)(LA + aoff[mt]);
        #pragma unroll
        for (int nt = 0; nt < 4; ++nt) bf[nt] = *(const v8h*)(LB + boff[nt]);
        #pragma unroll
        for (int mt = 0; mt < 5; ++mt)
            #pragma unroll
            for (int nt = 0; nt < 4; ++nt)
                acc[mt][nt] = __builtin_amdgcn_mfma_f32_16x16x32_f16(af[mt], bf[nt], acc[mt][nt], 0, 0, 0);
    }
    #undef LOADS

    // ---- epilogue: D row = q4*4+r (test: l,j), col = r15 (enroll: k,i) ----
    const float inv40 = 1.0f / (40.0f + 1e-6f);
    int lg = (m0 + wm) / PB;                           // wave covers groups lg, lg+1
    #pragma unroll
    for (int nt = 0; nt < 4; ++nt) {
        float s0 = 0.f, s1 = 0.f, t2 = 0.f;
        #pragma unroll
        for (int mt = 0; mt < 5; ++mt) {
            #pragma unroll
            for (int r = 0; r < 4; ++r) {
                float x = acc[mt][nt][r];
                float u = fmaf(x, 1024.0f, 1056.0f);
                int i = (int)u;
                i = min(max(i, 0), NTAB - 2);
                float f = u - (float)i;
                float g = fmaf(f, gslope[i], gval[i]);
                float xg = g * x;
                if (mt < 2)       s0 += xg;            // rows 0..31  -> group lg
                else if (mt == 2) t2 += xg;            // rows 32..47 -> straddle
                else              s1 += xg;            // rows 48..79 -> group lg+1
            }
        }
        bool lo = (q4 < 2);                            // mt=2: q4<2 -> rows 32..39 (lg)
        s0 += lo ? t2 : 0.f;
        s1 += lo ? 0.f : t2;
        s0 += __shfl_xor(s0, 16); s0 += __shfl_xor(s0, 32);
        s1 += __shfl_xor(s1, 16); s1 += __shfl_xor(s1, 32);
        if (q4 == 0) {
            int n = n0 + wn + nt * 16 + r15;
            int kk = n / PB, ii = n - kk * PB;
            pho2[((size_t)kk * KTR + lg)     * PB + ii] = s0 * inv40;
            pho2[((size_t)kk * KTR + lg + 1) * PB + ii] = s1 * inv40;
        }
    }
}

// ---------------- Kernel 3: gate (full range -> tanhf) + i-reduction -> [K,K] ----------------
__global__ __launch_bounds__(256) void k_final(const float* __restrict__ pho2,
                                               const float* __restrict__ fc1_w,
                                               const float* __restrict__ fc1_b,
                                               const float* __restrict__ fc2_w,
                                               float* __restrict__ out) {
    int wv = threadIdx.x >> 6;
    int lane = threadIdx.x & 63;
    int pair = blockIdx.x * 4 + wv;

    float w[CH], bb[CH], vv[CH];
    #pragma unroll
    for (int c = 0; c < CH; ++c) { w[c] = fc1_w[c]; bb[c] = fc1_b[c]; vv[c] = fc2_w[c]; }

    float x = (lane < PB) ? pho2[(size_t)pair * PB + lane] : 0.f;
    float s = gate_ref(x, w, bb, vv) * x;

    #pragma unroll
    for (int off = 32; off; off >>= 1) s += __shfl_xor(s, off);
    if (lane == 0) out[pair] = s / (40.0f + 1e-6f);
}

extern "C" void kernel_launch(void* const* d_in, const int* in_sizes, int n_in,
                              void* d_out, int out_size, void* d_ws, size_t ws_size,
                              hipStream_t stream) {
    const float* enroll = (const float*)d_in[0];
    const float* test   = (const float*)d_in[1];
    const float* fc1_w  = (const float*)d_in[2];
    const float* fc1_b  = (const float*)d_in[3];
    const float* fc2_w  = (const float*)d_in[4];
    float* out = (float*)d_out;

    _Float16* XT = (_Float16*)d_ws;                    // [3840][512] f16 (test:  hi|lo')
    _Float16* XE = XT + (size_t)MDIM * KK;             // [3840][512] f16 (enroll: lo'|hi)
    float* pho2  = (float*)(XE + (size_t)MDIM * KK);   // [96*96*40] f32
    float2* gtabG = (float2*)(pho2 + (size_t)KTR * KTR * PB);

    k_norm<<<2 * KTR + 9, 256, 0, stream>>>(enroll, test, fc1_w, fc1_b, fc2_w, XT, XE, gtabG);
    dim3 g2(MDIM / BN, MDIM / BM);                     // (30, 24)
    k_gemm<<<g2, 256, 0, stream>>>(XT, XE, gtabG, pho2);
    k_final<<<KTR * KTR / 4, 256, 0, stream>>>(pho2, fc1_w, fc1_b, fc2_w, out);
}